// Round 5
// baseline (246.140 us; speedup 1.0000x reference)
//
#include <hip/hip_runtime.h>
#include <stdint.h>
#include <math.h>

// BSRBF-KAN layer: out = relu(LN(x)) @ base_W^T + (bspline(LN(x)) + rbf(LN(x))) @ spline_W^T
// Round 5: FUSED — A is never materialized. One GEMM kernel with BM=64,
// BN=512 (full N), BK=64; W k-slices streamed from L2 via global_load_lds;
// the 64x64 A-tile (LN+relu / spline+rbf) is computed on the fly into LDS
// each K-step. LN stats computed in-kernel (8 lanes/row shuffle reduce).
//   ws: [W interleaved bf16: 512*4608]  (~4.5 MB)

#define D_IN  512
#define D_OUT 512
#define NB    8
#define KTOT  (D_IN + D_IN * NB)   // 4608
#define ROWS  16384                // B*S
#define NSTEP (KTOT / 64)          // 72
#define LDS_BYTES ((512 * 64 + 64 * 64) * 2)  // Wt 64KB + At 8KB = 73728

typedef __attribute__((ext_vector_type(8))) short short8;
typedef __attribute__((ext_vector_type(4))) float f32x4;

__device__ __forceinline__ unsigned f2bfu(float f) {
  union { float f; unsigned u; } v; v.f = f;
  return (v.u + 0x7fffu + ((v.u >> 16) & 1u)) >> 16;  // RNE, finite inputs
}
__device__ __forceinline__ short f2bf(float f) { return (short)f2bfu(f); }

// ---------------- weight prep: interleave + fp32->bf16 -------------------
__global__ __launch_bounds__(256) void wprep_kernel(
    const float* __restrict__ bw, const float* __restrict__ sw,
    short* __restrict__ W) {
  const int o = blockIdx.x;
  for (int k = threadIdx.x; k < KTOT; k += 256) {
    const float v = (k < D_IN) ? bw[o * D_IN + k]
                               : sw[(size_t)o * (D_IN * NB) + (k - D_IN)];
    W[(size_t)o * KTOT + k] = f2bf(v);
  }
}

// ---------------- fused LN + basis + GEMM --------------------------------
#define GLL(g, l)                                               \
  __builtin_amdgcn_global_load_lds(                             \
      (const __attribute__((address_space(1))) void*)(g),       \
      (__attribute__((address_space(3))) void*)(l), 16, 0, 0)

__global__ __launch_bounds__(512, 2) void fused_kernel(
    const float* __restrict__ x, const float* __restrict__ gamma,
    const float* __restrict__ beta, const short* __restrict__ W,
    float* __restrict__ out) {
  extern __shared__ short lds[];
  short* Wt = lds;            // 512 n-rows x 64 k; slot c of row n = chunk c^(n&7)
  short* At = lds + 512 * 64; // 64 m-rows  x 64 k; same swizzle
  const int tid = threadIdx.x;
  const int lane = tid & 63, wave = tid >> 6;
  const int m0 = blockIdx.x * 64;
  const int row = tid >> 3;   // 0..63 (m-row this thread computes; also Wt stage n-row)
  const int dl  = tid & 7;    // 0..7

  // ---- LN stats: 8 lanes per row, coalesced, shuffle-reduce over dl ----
  const float* xrow = x + (size_t)(m0 + row) * D_IN;
  float s = 0.0f, ss = 0.0f;
#pragma unroll
  for (int i = 0; i < 64; i++) {
    const float v = xrow[i * 8 + dl];
    s += v; ss += v * v;
  }
#pragma unroll
  for (int off = 1; off < 8; off <<= 1) {
    s += __shfl_xor(s, off);
    ss += __shfl_xor(ss, off);
  }
  const float mu = s * (1.0f / D_IN);
  const float var = ss * (1.0f / D_IN) - mu * mu;
  const float rstd = 1.0f / sqrtf(var + 1e-5f);

  const f32x4 zero = {0.0f, 0.0f, 0.0f, 0.0f};
  f32x4 acc[4][4];
#pragma unroll
  for (int i = 0; i < 4; i++)
#pragma unroll
    for (int j = 0; j < 4; j++) acc[i][j] = zero;

  // ---- Wt staging: thread (n-row r0 = tid>>3, chunk-slot c0 = tid&7),
  // 8 rounds of +64 rows; source chunk = c0 ^ (r0&7); (r0+64k)&7 invariant.
  const int qsrc = dl ^ (row & 7);
  const short* gW = W + (size_t)row * KTOT + qsrc * 8;

  // ---- At write: slot = dl ^ (row&7), 16B contiguous (matches frag reads)
  short* atw = At + row * 64 + (dl ^ (row & 7)) * 8;

  // ---- fragment read geometry (R2-R4 verified, 0 bank conflicts) ----
  const int lr = lane & 15;
  const int q  = lane >> 4;
  const int x7 = lr & 7;
  const int nbase = wave * 64;  // per-wave 64-col n-strip

  for (int c = 0; c < NSTEP; c++) {
    const int kt = c * 64;
    __syncthreads();
    // async-stage this K-step's W slice (512 n x 64 k = 64 KB) from L2
#pragma unroll
    for (int rd = 0; rd < 8; rd++)
      GLL(gW + (size_t)(64 * rd) * KTOT + kt, Wt + (64 * rd + 8 * wave) * 64);

    // compute this thread's 8 A values (overlaps the W fetch)
    short8 val;
    if (c < 8) {
      // relu region: k = kt + dl*8 + j  ->  d = k
      const int db = kt + dl * 8;
#pragma unroll
      for (int j = 0; j < 8; j++) {
        const float xn = (xrow[db + j] - mu) * rstd * gamma[db + j] + beta[db + j];
        val[j] = f2bf(fmaxf(xn, 0.0f));
      }
    } else {
      // spline region: chunk covers d in [8(c-8), 8(c-8)+8); this thread owns one d
      const int d = 8 * (c - 8) + dl;
      const float xn = (xrow[d] - mu) * rstd * gamma[d] + beta[d];
      // closed-form uniform cubic B-spline, knots (i-3)*0.6 - 1.5
      const float u = (xn + 3.3f) * (1.0f / 0.6f);
      const float cf = floorf(u);
      const int ci = (int)cf;
      const bool in = (ci >= 0) && (ci <= 10);
      const float t = u - cf;
      const float t2 = t * t, t3 = t2 * t;
      const float omt = 1.0f - t;
      float v0 = t3 * (1.0f / 6.0f);
      float v1 = (1.0f / 6.0f) * (1.0f + 3.0f * t + 3.0f * t2 - 3.0f * t3);
      float v2 = (1.0f / 6.0f) * (4.0f - 6.0f * t2 + 3.0f * t3);
      float v3 = (1.0f / 6.0f) * omt * omt * omt;
      if (!in) { v0 = 0.0f; v1 = 0.0f; v2 = 0.0f; v3 = 0.0f; }
#pragma unroll
      for (int j = 0; j < 8; j++) {
        const int m = ci - j;
        float sp = 0.0f;
        sp = (m == 0) ? v0 : sp;
        sp = (m == 1) ? v1 : sp;
        sp = (m == 2) ? v2 : sp;
        sp = (m == 3) ? v3 : sp;
        const float tt = (xn - (-1.5f + (float)j * (3.0f / 7.0f))) * (7.0f / 3.0f);
        const float rb = __builtin_amdgcn_exp2f(tt * tt * -1.442695040888963f);
        val[j] = f2bf(sp + rb);
      }
    }
    *(short8*)atw = val;  // ds_write_b128
    __syncthreads();

    // MFMA: wave computes 64 rows x its 64-col strip
#pragma unroll
    for (int h = 0; h < 2; h++) {
      const int gq = h * 4 + q;
      const int sl = (gq ^ x7) * 8;
      short8 af[4], bf[4];
#pragma unroll
      for (int mi = 0; mi < 4; mi++)
        af[mi] = *(const short8*)&At[(mi * 16 + lr) * 64 + sl];
#pragma unroll
      for (int nj = 0; nj < 4; nj++)
        bf[nj] = *(const short8*)&Wt[(nbase + nj * 16 + lr) * 64 + sl];
#pragma unroll
      for (int mi = 0; mi < 4; mi++)
#pragma unroll
        for (int nj = 0; nj < 4; nj++)
          acc[mi][nj] = __builtin_amdgcn_mfma_f32_16x16x32_bf16(
              af[mi], bf[nj], acc[mi][nj], 0, 0, 0);
    }
  }

  // C/D layout (m89-verified): col = lane&15, row = (lane>>4)*4 + reg
#pragma unroll
  for (int mi = 0; mi < 4; mi++) {
#pragma unroll
    for (int nj = 0; nj < 4; nj++) {
      const int gcol = nbase + nj * 16 + lr;
#pragma unroll
      for (int r = 0; r < 4; r++) {
        const int grow = m0 + mi * 16 + q * 4 + r;
        out[(size_t)grow * D_OUT + gcol] = acc[mi][nj][r];
      }
    }
  }
}

extern "C" void kernel_launch(void* const* d_in, const int* in_sizes, int n_in,
                              void* d_out, int out_size, void* d_ws, size_t ws_size,
                              hipStream_t stream) {
  const float* x     = (const float*)d_in[0];
  const float* gamma = (const float*)d_in[1];
  const float* beta  = (const float*)d_in[2];
  const float* bw    = (const float*)d_in[3];
  const float* sw    = (const float*)d_in[4];
  float* out = (float*)d_out;

  short* W = (short*)d_ws;  // 512 * 4608 bf16 interleaved [base | spline]

  (void)hipFuncSetAttribute(
      reinterpret_cast<const void*>(&fused_kernel),
      hipFuncAttributeMaxDynamicSharedMemorySize, LDS_BYTES);

  wprep_kernel<<<D_OUT, 256, 0, stream>>>(bw, sw, W);
  fused_kernel<<<ROWS / 64, 512, LDS_BYTES, stream>>>(x, gamma, beta, W, out);
}

// Round 6
// 237.396 us; speedup vs baseline: 1.0368x; 1.0368x over previous
//
#include <hip/hip_runtime.h>
#include <stdint.h>
#include <math.h>

// BSRBF-KAN layer: out = relu(LN(x)) @ base_W^T + (bspline(LN(x)) + rbf(LN(x))) @ spline_W^T
// Round 6: fused GEMM with L2-RESIDENT W panels.
//   BM=64, BN=256 (panel = blockIdx&1 -> one 2.36MB W panel per XCD-L2 via
//   round-robin block->XCD), BK=64, 256 threads, grid 512 = 2 blocks/CU.
//   A-tile (relu / spline+rbf) computed on the fly into LDS from a fp32 xn
//   prepass. A never touches HBM.
//   ws: [W: 512*4608 bf16 = 4.72MB][xn: 16384*512 f32 = 33.5MB]

#define D_IN  512
#define D_OUT 512
#define NB    8
#define KTOT  (D_IN + D_IN * NB)   // 4608
#define ROWS  16384                // B*S
#define NSTEP (KTOT / 64)          // 72

typedef __attribute__((ext_vector_type(8))) short short8;
typedef __attribute__((ext_vector_type(4))) float f32x4;

__device__ __forceinline__ unsigned f2bfu(float f) {
  union { float f; unsigned u; } v; v.f = f;
  return (v.u + 0x7fffu + ((v.u >> 16) & 1u)) >> 16;  // RNE, finite inputs
}
__device__ __forceinline__ short f2bf(float f) { return (short)f2bfu(f); }

// ---------------- weight prep: interleave + fp32->bf16 -------------------
__global__ __launch_bounds__(256) void wprep_kernel(
    const float* __restrict__ bw, const float* __restrict__ sw,
    short* __restrict__ W) {
  const int o = blockIdx.x;
  for (int k = threadIdx.x; k < KTOT; k += 256) {
    const float v = (k < D_IN) ? bw[o * D_IN + k]
                               : sw[(size_t)o * (D_IN * NB) + (k - D_IN)];
    W[(size_t)o * KTOT + k] = f2bf(v);
  }
}

// ---------------- LN prepass: xn fp32 ------------------------------------
// wave-per-row; lane owns d = e*64 + lane
__global__ __launch_bounds__(256) void ln_kernel(
    const float* __restrict__ x, const float* __restrict__ gamma,
    const float* __restrict__ beta, float* __restrict__ xn) {
  const int tid = threadIdx.x;
  const int lane = tid & 63, wave = tid >> 6;
  const int row = blockIdx.x * 4 + wave;
  const float* xr = x + (size_t)row * D_IN;

  float xv[8];
  float s = 0.0f, ss = 0.0f;
#pragma unroll
  for (int e = 0; e < 8; e++) {
    xv[e] = xr[e * 64 + lane];
    s += xv[e];
    ss += xv[e] * xv[e];
  }
#pragma unroll
  for (int off = 32; off > 0; off >>= 1) {
    s += __shfl_xor(s, off);
    ss += __shfl_xor(ss, off);
  }
  const float mu = s * (1.0f / D_IN);
  const float var = ss * (1.0f / D_IN) - mu * mu;
  const float rstd = 1.0f / sqrtf(var + 1e-5f);

  float* xo = xn + (size_t)row * D_IN;
#pragma unroll
  for (int e = 0; e < 8; e++) {
    const int d = e * 64 + lane;
    xo[d] = (xv[e] - mu) * rstd * gamma[d] + beta[d];
  }
}

// ---------------- fused basis + GEMM -------------------------------------
#define GLL(g, l)                                               \
  __builtin_amdgcn_global_load_lds(                             \
      (const __attribute__((address_space(1))) void*)(g),       \
      (__attribute__((address_space(3))) void*)(l), 16, 0, 0)

// one thread's 8 basis values (spline + rbf) for one xn value
__device__ __forceinline__ short8 basis8(float v) {
  const float u = (v + 3.3f) * (1.0f / 0.6f);
  const float cf = floorf(u);
  const int ci = (int)cf;
  const bool in = (ci >= 0) && (ci <= 10);
  const float t = u - cf;
  const float t2 = t * t, t3 = t2 * t;
  const float omt = 1.0f - t;
  float v0 = t3 * (1.0f / 6.0f);
  float v1 = (1.0f / 6.0f) * (1.0f + 3.0f * t + 3.0f * t2 - 3.0f * t3);
  float v2 = (1.0f / 6.0f) * (4.0f - 6.0f * t2 + 3.0f * t3);
  float v3 = (1.0f / 6.0f) * omt * omt * omt;
  if (!in) { v0 = 0.0f; v1 = 0.0f; v2 = 0.0f; v3 = 0.0f; }
  short8 r;
#pragma unroll
  for (int j = 0; j < 8; j++) {
    const int m = ci - j;
    float sp = 0.0f;
    sp = (m == 0) ? v0 : sp;
    sp = (m == 1) ? v1 : sp;
    sp = (m == 2) ? v2 : sp;
    sp = (m == 3) ? v3 : sp;
    // exp(-((v-g_j)*(7/3))^2) = exp2(K*(v-g_j)^2), K = -(7/3)^2*log2(e)
    const float dx = v - (-1.5f + (float)j * (3.0f / 7.0f));
    const float rb = __builtin_amdgcn_exp2f(dx * dx * -7.854720394633394f);
    r[j] = f2bf(sp + rb);
  }
  return r;
}

__global__ __launch_bounds__(256, 2) void fused_kernel(
    const float* __restrict__ xn, const short* __restrict__ W,
    float* __restrict__ out) {
  __shared__ short Wt[256 * 64];  // 32 KB: 256 n-rows x 64 k, swizzled chunks
  __shared__ short At[64 * 64];   // 8 KB:  64 m-rows  x 64 k, same swizzle
  const int tid = threadIdx.x;
  const int lane = tid & 63, wave = tid >> 6;
  const int f = blockIdx.x;
  const int p = f & 1;            // panel parity == XCD parity (round-robin)
  const int m0 = (f >> 1) * 64;
  const int n0 = p * 256;

  const f32x4 zero = {0.0f, 0.0f, 0.0f, 0.0f};
  f32x4 acc[4][4];
#pragma unroll
  for (int i = 0; i < 4; i++)
#pragma unroll
    for (int j = 0; j < 4; j++) acc[i][j] = zero;

  // staging geometry: thread -> (row r0 = tid>>3 in 0..31, chunk-slot c0 = tid&7)
  const int r0 = tid >> 3;
  const int c0 = tid & 7;
  const int qsrc = c0 ^ (r0 & 7);             // slot c0 of row r holds chunk qsrc
  const short* gW = W + (size_t)(n0 + r0) * KTOT + qsrc * 8;

  // A ownership: rows {r0, r0+32}, dim-lane dl = c0
  const int dl = c0;
  short* atw0 = At + r0 * 64 + (dl ^ (r0 & 7)) * 8;
  short* atw1 = At + (r0 + 32) * 64 + (dl ^ (r0 & 7)) * 8;
  const float* xr0 = xn + (size_t)(m0 + r0) * D_IN;
  const float* xr1 = xn + (size_t)(m0 + r0 + 32) * D_IN;

  // fragment read geometry (R2-R5 verified, 0 bank conflicts)
  const int lr = lane & 15;
  const int q  = lane >> 4;
  const int x7 = lr & 7;
  const int nbase = wave * 64;  // per-wave 64-col strip of the 256-col panel

  for (int c = 0; c < NSTEP; c++) {
    const int kt = c * 64;
    __syncthreads();
    // stage this K-step's W panel slice (256 x 64 = 32 KB) from resident L2
#pragma unroll
    for (int rd = 0; rd < 8; rd++)
      GLL(gW + (size_t)(32 * rd) * KTOT + kt, Wt + (32 * rd + 8 * wave) * 64);

    // compute this thread's two A chunks (overlaps the W fetch)
    short8 val0, val1;
    if (c < 8) {
      // relu region: k = kt + dl*8 + j, d = k
      const int db = kt + dl * 8;
#pragma unroll
      for (int j = 0; j < 8; j++) {
        val0[j] = f2bf(fmaxf(xr0[db + j], 0.0f));
        val1[j] = f2bf(fmaxf(xr1[db + j], 0.0f));
      }
    } else {
      const int d = 8 * (c - 8) + dl;
      val0 = basis8(xr0[d]);
      val1 = basis8(xr1[d]);
    }
    *(short8*)atw0 = val0;
    *(short8*)atw1 = val1;
    __syncthreads();

    // MFMA: each wave computes 64 rows x its 64-col strip
#pragma unroll
    for (int h = 0; h < 2; h++) {
      const int gq = h * 4 + q;
      const int sl = (gq ^ x7) * 8;
      short8 af[4], bf[4];
#pragma unroll
      for (int mi = 0; mi < 4; mi++)
        af[mi] = *(const short8*)&At[(mi * 16 + lr) * 64 + sl];
#pragma unroll
      for (int nj = 0; nj < 4; nj++)
        bf[nj] = *(const short8*)&Wt[(nbase + nj * 16 + lr) * 64 + sl];
#pragma unroll
      for (int mi = 0; mi < 4; mi++)
#pragma unroll
        for (int nj = 0; nj < 4; nj++)
          acc[mi][nj] = __builtin_amdgcn_mfma_f32_16x16x32_bf16(
              af[mi], bf[nj], acc[mi][nj], 0, 0, 0);
    }
  }

  // C/D layout (m89-verified): col = lane&15, row = (lane>>4)*4 + reg
#pragma unroll
  for (int mi = 0; mi < 4; mi++) {
#pragma unroll
    for (int nj = 0; nj < 4; nj++) {
      const int gcol = n0 + nbase + nj * 16 + lr;
#pragma unroll
      for (int r = 0; r < 4; r++) {
        const int grow = m0 + mi * 16 + q * 4 + r;
        out[(size_t)grow * D_OUT + gcol] = acc[mi][nj][r];
      }
    }
  }
}

extern "C" void kernel_launch(void* const* d_in, const int* in_sizes, int n_in,
                              void* d_out, int out_size, void* d_ws, size_t ws_size,
                              hipStream_t stream) {
  const float* x     = (const float*)d_in[0];
  const float* gamma = (const float*)d_in[1];
  const float* beta  = (const float*)d_in[2];
  const float* bw    = (const float*)d_in[3];
  const float* sw    = (const float*)d_in[4];
  float* out = (float*)d_out;

  short* W  = (short*)d_ws;                          // 4.72 MB
  float* xn = (float*)((short*)d_ws + (size_t)D_OUT * KTOT);  // 33.5 MB

  wprep_kernel<<<D_OUT, 256, 0, stream>>>(bw, sw, W);
  ln_kernel<<<ROWS / 4, 256, 0, stream>>>(x, gamma, beta, xn);
  fused_kernel<<<ROWS / 64 * 2, 256, 0, stream>>>(xn, W, out);
}

// Round 7
// 229.859 us; speedup vs baseline: 1.0708x; 1.0328x over previous
//
#include <hip/hip_runtime.h>
#include <stdint.h>
#include <math.h>

// BSRBF-KAN layer: out = relu(LN(x)) @ base_W^T + (bspline(LN(x)) + rbf(LN(x))) @ spline_W^T
// Round 7: fused GEMM, basis via 512-entry LDS lerp TABLE (kills the VALU
// bottleneck measured in R6: 53% VALUBusy from closed-form spline+exp).
//   BM=128, BN=256 (panel = blockIdx&1 -> W panel L2-resident per XCD),
//   BK=64, 512 threads (8 waves), grid 256 = 1 block/CU.
//   Double-buffered Wt/At, ONE barrier per K-step: next-step staging
//   (GLL W + table lookups) interleaves with current-step MFMA.
//   ws: [W 4.72MB][xn f32 33.5MB][table 40KB]

#define D_IN  512
#define D_OUT 512
#define NB    8
#define KTOT  (D_IN + D_IN * NB)   // 4608
#define ROWS  16384                // B*S
#define NSTEP (KTOT / 64)          // 72
#define TABN  512                  // table entries over [-4,4], h = 1/64
#define LDSB  139264               // 2*(32K Wt + 16K At) + 40K table

typedef __attribute__((ext_vector_type(8))) short short8;
typedef __attribute__((ext_vector_type(4))) float f32x4;

__device__ __forceinline__ unsigned f2bfu(float f) {
  union { float f; unsigned u; } v; v.f = f;
  return (v.u + 0x7fffu + ((v.u >> 16) & 1u)) >> 16;  // RNE, finite inputs
}
__device__ __forceinline__ short f2bf(float f) { return (short)f2bfu(f); }

// ---------------- weight prep: interleave + fp32->bf16 -------------------
__global__ __launch_bounds__(256) void wprep_kernel(
    const float* __restrict__ bw, const float* __restrict__ sw,
    short* __restrict__ W) {
  const int o = blockIdx.x;
  for (int k = threadIdx.x; k < KTOT; k += 256) {
    const float v = (k < D_IN) ? bw[o * D_IN + k]
                               : sw[(size_t)o * (D_IN * NB) + (k - D_IN)];
    W[(size_t)o * KTOT + k] = f2bf(v);
  }
}

// ---------------- LN prepass: xn fp32 ------------------------------------
__global__ __launch_bounds__(256) void ln_kernel(
    const float* __restrict__ x, const float* __restrict__ gamma,
    const float* __restrict__ beta, float* __restrict__ xn) {
  const int tid = threadIdx.x;
  const int lane = tid & 63, wave = tid >> 6;
  const int row = blockIdx.x * 4 + wave;
  const float* xr = x + (size_t)row * D_IN;

  float xv[8];
  float s = 0.0f, ss = 0.0f;
#pragma unroll
  for (int e = 0; e < 8; e++) {
    xv[e] = xr[e * 64 + lane];
    s += xv[e];
    ss += xv[e] * xv[e];
  }
#pragma unroll
  for (int off = 32; off > 0; off >>= 1) {
    s += __shfl_xor(s, off);
    ss += __shfl_xor(ss, off);
  }
  const float mu = s * (1.0f / D_IN);
  const float var = ss * (1.0f / D_IN) - mu * mu;
  const float rstd = 1.0f / sqrtf(var + 1e-5f);

  float* xo = xn + (size_t)row * D_IN;
#pragma unroll
  for (int e = 0; e < 8; e++) {
    const int d = e * 64 + lane;
    xo[d] = (xv[e] - mu) * rstd * gamma[d] + beta[d];
  }
}

// ---------------- exact basis (f32), used only to build the table --------
__device__ __forceinline__ void basis8f(float v, float* o) {
  const float u = (v + 3.3f) * (1.0f / 0.6f);
  const float cf = floorf(u);
  const int ci = (int)cf;
  const bool in = (ci >= 0) && (ci <= 10);
  const float t = u - cf;
  const float t2 = t * t, t3 = t2 * t;
  const float omt = 1.0f - t;
  float v0 = t3 * (1.0f / 6.0f);
  float v1 = (1.0f / 6.0f) * (1.0f + 3.0f * t + 3.0f * t2 - 3.0f * t3);
  float v2 = (1.0f / 6.0f) * (4.0f - 6.0f * t2 + 3.0f * t3);
  float v3 = (1.0f / 6.0f) * omt * omt * omt;
  if (!in) { v0 = 0.0f; v1 = 0.0f; v2 = 0.0f; v3 = 0.0f; }
#pragma unroll
  for (int j = 0; j < 8; j++) {
    const int m = ci - j;
    float sp = 0.0f;
    sp = (m == 0) ? v0 : sp;
    sp = (m == 1) ? v1 : sp;
    sp = (m == 2) ? v2 : sp;
    sp = (m == 3) ? v3 : sp;
    const float dx = v - (-1.5f + (float)j * (3.0f / 7.0f));
    const float rb = __builtin_amdgcn_exp2f(dx * dx * -7.854720394633394f);
    o[j] = sp + rb;
  }
}

// ---------------- table prep: 512 entries x (f[8], df[8], pad[4]) --------
__global__ __launch_bounds__(256) void tabprep_kernel(float* __restrict__ Tg) {
  for (int i = threadIdx.x; i < TABN; i += 256) {
    float f0[8], f1[8];
    basis8f(-4.0f + (float)i * (1.0f / 64.0f), f0);
    basis8f(-4.0f + (float)(i + 1) * (1.0f / 64.0f), f1);
#pragma unroll
    for (int j = 0; j < 8; j++) {
      Tg[i * 20 + j] = f0[j];
      Tg[i * 20 + 8 + j] = f1[j] - f0[j];
    }
  }
}

// ---------------- fused basis-lookup + GEMM ------------------------------
#define GLL(g, l)                                               \
  __builtin_amdgcn_global_load_lds(                             \
      (const __attribute__((address_space(1))) void*)(g),       \
      (__attribute__((address_space(3))) void*)(l), 16, 0, 0)

__device__ __forceinline__ void tab8(const float* __restrict__ Tab, float v,
                                     float* o) {
  float u = fmaf(v, 64.0f, 256.0f);
  u = fminf(fmaxf(u, 0.0f), 511.0f);
  const float fi = floorf(u);
  const float t = u - fi;
  const int idx = (int)fi;
  const float* e = Tab + idx * 20;  // 80 B stride: uniform bank coverage
  const float4 f0 = *(const float4*)(e);
  const float4 f1 = *(const float4*)(e + 4);
  const float4 d0 = *(const float4*)(e + 8);
  const float4 d1 = *(const float4*)(e + 12);
  o[0] = fmaf(t, d0.x, f0.x); o[1] = fmaf(t, d0.y, f0.y);
  o[2] = fmaf(t, d0.z, f0.z); o[3] = fmaf(t, d0.w, f0.w);
  o[4] = fmaf(t, d1.x, f1.x); o[5] = fmaf(t, d1.y, f1.y);
  o[6] = fmaf(t, d1.z, f1.z); o[7] = fmaf(t, d1.w, f1.w);
}

__device__ __forceinline__ uint4 pack8(const float* o) {
  uint4 r;
  r.x = f2bfu(o[0]) | (f2bfu(o[1]) << 16);
  r.y = f2bfu(o[2]) | (f2bfu(o[3]) << 16);
  r.z = f2bfu(o[4]) | (f2bfu(o[5]) << 16);
  r.w = f2bfu(o[6]) | (f2bfu(o[7]) << 16);
  return r;
}

__global__ __launch_bounds__(512, 1) void fused_kernel(
    const float* __restrict__ xn, const short* __restrict__ W,
    const float* __restrict__ Tg, float* __restrict__ out) {
  extern __shared__ short lds[];
  short* const Wt0 = lds;            // 16384 shorts (32 KB)
  short* const At0 = lds + 16384;    // 8192 shorts (16 KB)
  short* const Wt1 = lds + 24576;
  short* const At1 = lds + 40960;
  float* const Tab = (float*)(lds + 49152);  // 40 KB

  const int tid = threadIdx.x;
  const int lane = tid & 63, wave = tid >> 6;
  const int f = blockIdx.x;
  const int p = f & 1;               // panel parity ~ XCD parity (round-robin)
  const int m0 = (f >> 1) * 128;
  const int n0 = p * 256;
  const int wm = wave & 1, wn = wave >> 1;   // 2 m-halves x 4 n-strips

  const f32x4 zero = {0.0f, 0.0f, 0.0f, 0.0f};
  f32x4 acc[4][4];
#pragma unroll
  for (int i = 0; i < 4; i++)
#pragma unroll
    for (int j = 0; j < 4; j++) acc[i][j] = zero;

  // W staging geometry: thread -> (row r0 = tid>>3 in 0..63, slot c0 = tid&7)
  const int r0 = tid >> 3;
  const int c0 = tid & 7;
  const int qsrc = c0 ^ (r0 & 7);    // slot c0 of row r holds chunk qsrc
  const short* gW = W + (size_t)(n0 + r0) * KTOT + qsrc * 8;
  const int wdst = wave * 512;       // wave-uniform LDS dest (+ rd*4096)

  // A ownership: rows {r0, r0+64}, dim-lane dl = c0; same XOR swizzle
  const int atoff = r0 * 64 + (c0 ^ (r0 & 7)) * 8;
  const int atoff1 = atoff + 64 * 64;
  const float* xr0 = xn + (size_t)(m0 + r0) * D_IN;
  const float* xr1 = xn + (size_t)(m0 + r0 + 64) * D_IN;

  // fragment read geometry (R2-R6 verified, 0 conflicts)
  const int lr = lane & 15;
  const int q = lane >> 4;
  const int x7 = lr & 7;

  // ---- one-time: stage the 40 KB table (8 waves x 5 KB) ----
  {
    const char* tg = (const char*)Tg + lane * 16;
    char* tb = (char*)Tab;
#pragma unroll
    for (int i = 0; i < 5; i++) {
      const int ch = wave * 5 + i;
      GLL(tg + ch * 1024, tb + ch * 1024);
    }
  }

  auto stage = [&](int c, short* Wt, short* At) {
    const int kt = c * 64;
#pragma unroll
    for (int rd = 0; rd < 4; rd++)
      GLL(gW + (size_t)(64 * rd) * KTOT + kt, Wt + wdst + rd * 4096);
    uint4 v0, v1;
    if (c < 8) {
      const int db = kt + c0 * 8;   // relu region: d = k
      const float4 a0 = *(const float4*)&xr0[db];
      const float4 a1 = *(const float4*)&xr0[db + 4];
      const float4 b0 = *(const float4*)&xr1[db];
      const float4 b1 = *(const float4*)&xr1[db + 4];
      v0.x = f2bfu(fmaxf(a0.x, 0.f)) | (f2bfu(fmaxf(a0.y, 0.f)) << 16);
      v0.y = f2bfu(fmaxf(a0.z, 0.f)) | (f2bfu(fmaxf(a0.w, 0.f)) << 16);
      v0.z = f2bfu(fmaxf(a1.x, 0.f)) | (f2bfu(fmaxf(a1.y, 0.f)) << 16);
      v0.w = f2bfu(fmaxf(a1.z, 0.f)) | (f2bfu(fmaxf(a1.w, 0.f)) << 16);
      v1.x = f2bfu(fmaxf(b0.x, 0.f)) | (f2bfu(fmaxf(b0.y, 0.f)) << 16);
      v1.y = f2bfu(fmaxf(b0.z, 0.f)) | (f2bfu(fmaxf(b0.w, 0.f)) << 16);
      v1.z = f2bfu(fmaxf(b1.x, 0.f)) | (f2bfu(fmaxf(b1.y, 0.f)) << 16);
      v1.w = f2bfu(fmaxf(b1.z, 0.f)) | (f2bfu(fmaxf(b1.w, 0.f)) << 16);
    } else {
      const int d = 8 * (c - 8) + c0;  // spline region: one dim per thread
      float o0[8], o1[8];
      tab8(Tab, xr0[d], o0);
      tab8(Tab, xr1[d], o1);
      v0 = pack8(o0);
      v1 = pack8(o1);
    }
    *(uint4*)(At + atoff) = v0;
    *(uint4*)(At + atoff1) = v1;
  };

  auto mfma_step = [&](const short* Wt, const short* At) {
#pragma unroll
    for (int h = 0; h < 2; h++) {
      const int sl = ((h * 4 + q) ^ x7) * 8;
      short8 af[4], bf[4];
#pragma unroll
      for (int mi = 0; mi < 4; mi++)
        af[mi] = *(const short8*)&At[(wm * 64 + mi * 16 + lr) * 64 + sl];
#pragma unroll
      for (int nj = 0; nj < 4; nj++)
        bf[nj] = *(const short8*)&Wt[(wn * 64 + nj * 16 + lr) * 64 + sl];
#pragma unroll
      for (int mi = 0; mi < 4; mi++)
#pragma unroll
        for (int nj = 0; nj < 4; nj++)
          acc[mi][nj] = __builtin_amdgcn_mfma_f32_16x16x32_bf16(
              af[mi], bf[nj], acc[mi][nj], 0, 0, 0);
    }
  };

  // prologue: buf0 <- step 0
  stage(0, Wt0, At0);
  __syncthreads();

  for (int c = 0; c < NSTEP; c += 2) {
    stage(c + 1, Wt1, At1);          // overlaps with MFMA below (indep stream)
    mfma_step(Wt0, At0);
    __syncthreads();
    if (c + 2 < NSTEP) stage(c + 2, Wt0, At0);
    mfma_step(Wt1, At1);
    __syncthreads();
  }

  // C/D layout (m89-verified): col = lane&15, row = (lane>>4)*4 + reg
#pragma unroll
  for (int mi = 0; mi < 4; mi++) {
#pragma unroll
    for (int nj = 0; nj < 4; nj++) {
      const int gcol = n0 + wn * 64 + nj * 16 + lr;
#pragma unroll
      for (int r = 0; r < 4; r++) {
        const int grow = m0 + wm * 64 + mi * 16 + q * 4 + r;
        out[(size_t)grow * D_OUT + gcol] = acc[mi][nj][r];
      }
    }
  }
}

extern "C" void kernel_launch(void* const* d_in, const int* in_sizes, int n_in,
                              void* d_out, int out_size, void* d_ws, size_t ws_size,
                              hipStream_t stream) {
  const float* x     = (const float*)d_in[0];
  const float* gamma = (const float*)d_in[1];
  const float* beta  = (const float*)d_in[2];
  const float* bw    = (const float*)d_in[3];
  const float* sw    = (const float*)d_in[4];
  float* out = (float*)d_out;

  short* W  = (short*)d_ws;                                   // 4.72 MB
  float* xn = (float*)((char*)d_ws + (size_t)D_OUT * KTOT * 2);       // 33.5 MB
  float* Tg = (float*)((char*)d_ws + (size_t)D_OUT * KTOT * 2 + (size_t)ROWS * D_IN * 4);  // 40 KB

  (void)hipFuncSetAttribute(
      reinterpret_cast<const void*>(&fused_kernel),
      hipFuncAttributeMaxDynamicSharedMemorySize, LDSB);

  wprep_kernel<<<D_OUT, 256, 0, stream>>>(bw, sw, W);
  ln_kernel<<<ROWS / 4, 256, 0, stream>>>(x, gamma, beta, xn);
  tabprep_kernel<<<1, 256, 0, stream>>>(Tg);
  fused_kernel<<<ROWS / 128 * 2, 512, LDSB, stream>>>(xn, W, Tg, out);
}

// Round 8
// 222.745 us; speedup vs baseline: 1.1050x; 1.0319x over previous
//
#include <hip/hip_runtime.h>
#include <stdint.h>
#include <math.h>

// BSRBF-KAN layer: out = relu(LN(x)) @ base_W^T + (bspline(LN(x)) + rbf(LN(x))) @ spline_W^T
// Round 8: fused GEMM, bf16 lerp table (halves table LDS traffic), back to
// 2 blocks/CU for cross-block barrier overlap (m114).
//   BM=64, BN=256 (panel = f&1, L2-resident per XCD parity), BK=64,
//   256 threads (4 waves, wave out = 64x64), single-buffered, grid 512.
//   LDS: Wt 32K + At 8K + table 24K = 64K -> 2 blocks/CU.
//   ws: [W 4.72MB][xn f32 33.5MB][tab bf16 24KB]

#define D_IN  512
#define D_OUT 512
#define NB    8
#define KTOT  (D_IN + D_IN * NB)   // 4608
#define ROWS  16384                // B*S
#define NSTEP (KTOT / 64)          // 72
#define TABN  512                  // entries over [-4,4], h = 1/64
#define TSTR  24                   // shorts per entry (48 B, 16B-aligned)
#define LDSB  65536

typedef __attribute__((ext_vector_type(8))) short short8;
typedef __attribute__((ext_vector_type(4))) float f32x4;

__device__ __forceinline__ unsigned f2bfu(float f) {
  union { float f; unsigned u; } v; v.f = f;
  return (v.u + 0x7fffu + ((v.u >> 16) & 1u)) >> 16;  // RNE, finite inputs
}
__device__ __forceinline__ short f2bf(float f) { return (short)f2bfu(f); }
__device__ __forceinline__ float bfhi(unsigned w) {  // high bf16 of word
  union { unsigned u; float f; } v; v.u = w & 0xffff0000u; return v.f;
}
__device__ __forceinline__ float bflo(unsigned w) {  // low bf16 of word
  union { unsigned u; float f; } v; v.u = w << 16; return v.f;
}

// ---------------- weight prep: interleave + fp32->bf16 -------------------
__global__ __launch_bounds__(256) void wprep_kernel(
    const float* __restrict__ bw, const float* __restrict__ sw,
    short* __restrict__ W) {
  const int o = blockIdx.x;
  for (int k = threadIdx.x; k < KTOT; k += 256) {
    const float v = (k < D_IN) ? bw[o * D_IN + k]
                               : sw[(size_t)o * (D_IN * NB) + (k - D_IN)];
    W[(size_t)o * KTOT + k] = f2bf(v);
  }
}

// ---------------- LN prepass: xn fp32 ------------------------------------
__global__ __launch_bounds__(256) void ln_kernel(
    const float* __restrict__ x, const float* __restrict__ gamma,
    const float* __restrict__ beta, float* __restrict__ xn) {
  const int tid = threadIdx.x;
  const int lane = tid & 63, wave = tid >> 6;
  const int row = blockIdx.x * 4 + wave;
  const float* xr = x + (size_t)row * D_IN;

  float xv[8];
  float s = 0.0f, ss = 0.0f;
#pragma unroll
  for (int e = 0; e < 8; e++) {
    xv[e] = xr[e * 64 + lane];
    s += xv[e];
    ss += xv[e] * xv[e];
  }
#pragma unroll
  for (int off = 32; off > 0; off >>= 1) {
    s += __shfl_xor(s, off);
    ss += __shfl_xor(ss, off);
  }
  const float mu = s * (1.0f / D_IN);
  const float var = ss * (1.0f / D_IN) - mu * mu;
  const float rstd = 1.0f / sqrtf(var + 1e-5f);

  float* xo = xn + (size_t)row * D_IN;
#pragma unroll
  for (int e = 0; e < 8; e++) {
    const int d = e * 64 + lane;
    xo[d] = (xv[e] - mu) * rstd * gamma[d] + beta[d];
  }
}

// ---------------- exact basis (f32), table build only --------------------
__device__ __forceinline__ void basis8f(float v, float* o) {
  const float u = (v + 3.3f) * (1.0f / 0.6f);
  const float cf = floorf(u);
  const int ci = (int)cf;
  const bool in = (ci >= 0) && (ci <= 10);
  const float t = u - cf;
  const float t2 = t * t, t3 = t2 * t;
  const float omt = 1.0f - t;
  float v0 = t3 * (1.0f / 6.0f);
  float v1 = (1.0f / 6.0f) * (1.0f + 3.0f * t + 3.0f * t2 - 3.0f * t3);
  float v2 = (1.0f / 6.0f) * (4.0f - 6.0f * t2 + 3.0f * t3);
  float v3 = (1.0f / 6.0f) * omt * omt * omt;
  if (!in) { v0 = 0.0f; v1 = 0.0f; v2 = 0.0f; v3 = 0.0f; }
#pragma unroll
  for (int j = 0; j < 8; j++) {
    const int m = ci - j;
    float sp = 0.0f;
    sp = (m == 0) ? v0 : sp;
    sp = (m == 1) ? v1 : sp;
    sp = (m == 2) ? v2 : sp;
    sp = (m == 3) ? v3 : sp;
    const float dx = v - (-1.5f + (float)j * (3.0f / 7.0f));
    const float rb = __builtin_amdgcn_exp2f(dx * dx * -7.854720394633394f);
    o[j] = sp + rb;
  }
}

// ---------------- table prep: bf16 {f[8], df[8], pad[8]} per entry -------
__global__ __launch_bounds__(256) void tabprep_kernel(short* __restrict__ Tg) {
  for (int i = threadIdx.x; i < TABN; i += 256) {
    float f0[8], f1[8];
    basis8f(-4.0f + (float)i * (1.0f / 64.0f), f0);
    basis8f(-4.0f + (float)(i + 1) * (1.0f / 64.0f), f1);
#pragma unroll
    for (int j = 0; j < 8; j++) {
      Tg[i * TSTR + j] = f2bf(f0[j]);
      Tg[i * TSTR + 8 + j] = f2bf(f1[j] - f0[j]);
      Tg[i * TSTR + 16 + j] = 0;
    }
  }
}

// ---------------- fused basis-lookup + GEMM ------------------------------
#define GLL(g, l)                                               \
  __builtin_amdgcn_global_load_lds(                             \
      (const __attribute__((address_space(1))) void*)(g),       \
      (__attribute__((address_space(3))) void*)(l), 16, 0, 0)

__device__ __forceinline__ uint4 tab8(const short* __restrict__ Tab, float v) {
  float u = fmaf(v, 64.0f, 256.0f);
  u = fminf(fmaxf(u, 0.0f), 511.0f);
  const float fi = floorf(u);
  const float t = u - fi;
  const int idx = (int)fi;
  const short* e = Tab + idx * TSTR;         // 48 B stride, 16B-aligned
  const short8 fv = *(const short8*)e;       // ds_read_b128
  const short8 dv = *(const short8*)(e + 8); // ds_read_b128
  const unsigned* fw = (const unsigned*)&fv;
  const unsigned* dw = (const unsigned*)&dv;
  uint4 r;
  unsigned* rp = (unsigned*)&r;
#pragma unroll
  for (int h = 0; h < 4; h++) {
    const float rl = fmaf(t, bflo(dw[h]), bflo(fw[h]));
    const float rh = fmaf(t, bfhi(dw[h]), bfhi(fw[h]));
    rp[h] = f2bfu(rl) | (f2bfu(rh) << 16);
  }
  return r;
}

__device__ __forceinline__ uint4 relu8(const float* p) {
  const float4 a = *(const float4*)p;
  const float4 b = *(const float4*)(p + 4);
  uint4 r;
  r.x = f2bfu(fmaxf(a.x, 0.f)) | (f2bfu(fmaxf(a.y, 0.f)) << 16);
  r.y = f2bfu(fmaxf(a.z, 0.f)) | (f2bfu(fmaxf(a.w, 0.f)) << 16);
  r.z = f2bfu(fmaxf(b.x, 0.f)) | (f2bfu(fmaxf(b.y, 0.f)) << 16);
  r.w = f2bfu(fmaxf(b.z, 0.f)) | (f2bfu(fmaxf(b.w, 0.f)) << 16);
  return r;
}

__global__ __launch_bounds__(256, 2) void fused_kernel(
    const float* __restrict__ xn, const short* __restrict__ W,
    const short* __restrict__ Tg, float* __restrict__ out) {
  extern __shared__ short lds[];
  short* const Wt = lds;              // 256 x 64 = 16384 shorts (32 KB)
  short* const At = lds + 16384;      // 64 x 64  = 4096 shorts (8 KB)
  short* const Tab = lds + 20480;     // 512 x 24 = 12288 shorts (24 KB)

  const int tid = threadIdx.x;
  const int lane = tid & 63, wave = tid >> 6;
  const int f = blockIdx.x;
  const int p = f & 1;                // panel parity == XCD parity heuristic
  const int m0 = (f >> 1) * 64;
  const int n0 = p * 256;

  const f32x4 zero = {0.0f, 0.0f, 0.0f, 0.0f};
  f32x4 acc[4][4];
#pragma unroll
  for (int i = 0; i < 4; i++)
#pragma unroll
    for (int j = 0; j < 4; j++) acc[i][j] = zero;

  // staging geometry: thread -> (row r0 = tid>>3 in 0..31, slot c0 = tid&7)
  const int r0 = tid >> 3;
  const int c0 = tid & 7;
  const int qsrc = c0 ^ (r0 & 7);     // slot c0 of row r holds chunk qsrc
  const short* gW = W + (size_t)(n0 + r0) * KTOT + qsrc * 8;
  const int wdst = wave * 512;        // + rd*2048: wave-uniform GLL dest

  // At ownership: rows {r0, r0+32}, dim-lane c0; same XOR swizzle
  const int atoff0 = r0 * 64 + (c0 ^ (r0 & 7)) * 8;
  const int atoff1 = atoff0 + 32 * 64;
  const float* xr0 = xn + (size_t)(m0 + r0) * D_IN;
  const float* xr1 = xn + (size_t)(m0 + r0 + 32) * D_IN;

  // fragment read geometry (R2-R7 verified, 0 conflicts)
  const int lr = lane & 15;
  const int q = lane >> 4;
  const int x7 = lr & 7;

  // one-time: stage the 24 KB table (4 waves x 6 KB)
  {
    const char* tg = (const char*)Tg + lane * 16;
    char* tb = (char*)Tab;
#pragma unroll
    for (int i = 0; i < 6; i++) {
      const int ch = wave * 6 + i;
      GLL(tg + ch * 1024, tb + ch * 1024);
    }
  }

  for (int c = 0; c < NSTEP; c++) {
    const int kt = c * 64;
    __syncthreads();  // drains prior-step frag reads (and table GLL at c=0)
    // stage W slice (256 x 64 = 32 KB) from L2-resident panel
#pragma unroll
    for (int rd = 0; rd < 8; rd++)
      GLL(gW + (size_t)(32 * rd) * KTOT + kt, Wt + wdst + rd * 2048);
    // compute this thread's two At chunks
    uint4 v0, v1;
    if (c < 8) {
      const int db = kt + c0 * 8;     // relu region: d = k
      v0 = relu8(&xr0[db]);
      v1 = relu8(&xr1[db]);
    } else {
      const int d = 8 * (c - 8) + c0; // spline region: one dim per thread
      v0 = tab8(Tab, xr0[d]);
      v1 = tab8(Tab, xr1[d]);
    }
    *(uint4*)(At + atoff0) = v0;
    *(uint4*)(At + atoff1) = v1;
    __syncthreads();

    // MFMA: each wave computes 64 rows x its 64-col strip
#pragma unroll
    for (int h = 0; h < 2; h++) {
      const int sl = ((h * 4 + q) ^ x7) * 8;
      short8 af[4], bf[4];
#pragma unroll
      for (int mi = 0; mi < 4; mi++)
        af[mi] = *(const short8*)&At[(mi * 16 + lr) * 64 + sl];
#pragma unroll
      for (int nj = 0; nj < 4; nj++)
        bf[nj] = *(const short8*)&Wt[(wave * 64 + nj * 16 + lr) * 64 + sl];
#pragma unroll
      for (int mi = 0; mi < 4; mi++)
#pragma unroll
        for (int nj = 0; nj < 4; nj++)
          acc[mi][nj] = __builtin_amdgcn_mfma_f32_16x16x32_bf16(
              af[mi], bf[nj], acc[mi][nj], 0, 0, 0);
    }
  }

  // C/D layout (m89-verified): col = lane&15, row = (lane>>4)*4 + reg
#pragma unroll
  for (int mi = 0; mi < 4; mi++) {
#pragma unroll
    for (int nj = 0; nj < 4; nj++) {
      const int gcol = n0 + wave * 64 + nj * 16 + lr;
#pragma unroll
      for (int r = 0; r < 4; r++) {
        const int grow = m0 + mi * 16 + q * 4 + r;
        out[(size_t)grow * D_OUT + gcol] = acc[mi][nj][r];
      }
    }
  }
}

extern "C" void kernel_launch(void* const* d_in, const int* in_sizes, int n_in,
                              void* d_out, int out_size, void* d_ws, size_t ws_size,
                              hipStream_t stream) {
  const float* x     = (const float*)d_in[0];
  const float* gamma = (const float*)d_in[1];
  const float* beta  = (const float*)d_in[2];
  const float* bw    = (const float*)d_in[3];
  const float* sw    = (const float*)d_in[4];
  float* out = (float*)d_out;

  short* W  = (short*)d_ws;                                        // 4.72 MB
  float* xn = (float*)((char*)d_ws + (size_t)D_OUT * KTOT * 2);    // 33.5 MB
  short* Tg = (short*)((char*)d_ws + (size_t)D_OUT * KTOT * 2 +
                       (size_t)ROWS * D_IN * 4);                   // 24 KB

  (void)hipFuncSetAttribute(
      reinterpret_cast<const void*>(&fused_kernel),
      hipFuncAttributeMaxDynamicSharedMemorySize, LDSB);

  wprep_kernel<<<D_OUT, 256, 0, stream>>>(bw, sw, W);
  ln_kernel<<<ROWS / 4, 256, 0, stream>>>(x, gamma, beta, xn);
  tabprep_kernel<<<1, 256, 0, stream>>>(Tg);
  fused_kernel<<<ROWS / 64 * 2, 256, LDSB, stream>>>(xn, W, Tg, out);
}